// Round 15
// baseline (481.494 us; speedup 1.0000x reference)
//
#include <hip/hip_runtime.h>
#include <stdint.h>

// ---------------------------------------------------------------------------
// ColorExtractor: per-image k-means (B=64, H*W=50176, C=3, K=16, 10 iters).
// Threefry2x32 bit-exact (verified R1, absmax 0.0).
// R14: vectorize the LDS accumulator RMW. R13 (rolled 1-ahead pipeline,
// 88 VGPR, no spill, 2 blk/CU) = best verified at 434-447us. Remaining
// idle ~280us; largest in-loop latency = 16 scalar LDS RMW chains/stage
// (ds_read ~120cy -> add -> ds_write, x4 per quad).
// Fix: transpose accf from [cluster*4+comp][tid] to [tid][68] (16 clusters
// x 4 comps + 4-float pad). The 4 component adds per quad become ONE
// ds_read_b128 + 4 v_add + ONE ds_write_b128 (1/4 the LDS ops, 1 latency
// chain per quad). Stride 68 floats (272B): bank = (4 tid + 4 best + c)%32
// -> 8 dwords/bank for wave64 b128 = conflict-free minimum (pad essential:
// stride 64 puts all lanes on 4 banks). LDS 64->68KB, still 2 blk/CU.
// Numerics: per-thread per-address f32 add order UNCHANGED; f64 reduce
// reads the same logical elements in the same rotated order (re-addressed
// only). absmax must stay 0.0.
// Config (locked by R7-R13 map): launch_bounds(256,2) -> 128-VGPR cap +
// 2 blk/CU; rolled pipeline fits at ~88 VGPR.
// R7 kept: per-batch 8-block barriers (monotonic counter), release-only
// light barriers + agent atomics in the loop, full acq/rel in init.
// ---------------------------------------------------------------------------

#define NB    64
#define NPIX  50176
#define NK    16
#define NCH   3
#define NITER 10
#define HBINS 2048
#define CANDCAP 1024     // expect ~320 cands/batch (T2VAL), huge margin
#define COLLCAP 128      // expect ~24.5/bin
#define NBLK  512        // 8 chunks x 64 batches; 2 blocks/CU on 256 CUs
#define CHUNK (NPIX / 8) // 6272 px per block-chunk
#define NQUADS (CHUNK / 4)  // 1568 = 6*256 + 32
#define TSTRIDE 68       // per-thread accf stride: 16*4 + 4 pad (bank spread)

typedef unsigned long long u64;

struct KeyPair { uint32_t a, b; };

__device__ __forceinline__ uint32_t rotl32(uint32_t v, uint32_t r) {
  return (v << r) | (v >> (32u - r));
}
__device__ __forceinline__ void tf_round(uint32_t& x0, uint32_t& x1, uint32_t r) {
  x0 += x1; x1 = rotl32(x1, r); x1 ^= x0;
}

// Threefry-2x32, 20 rounds, exactly as jax/_src/prng.py lowering.
__device__ __forceinline__ KeyPair threefry(uint32_t k0, uint32_t k1,
                                            uint32_t x0, uint32_t x1) {
  const uint32_t ks2 = k0 ^ k1 ^ 0x1BD11BDAu;
  x0 += k0; x1 += k1;
  tf_round(x0, x1, 13u); tf_round(x0, x1, 15u); tf_round(x0, x1, 26u); tf_round(x0, x1, 6u);
  x0 += k1;  x1 += ks2 + 1u;
  tf_round(x0, x1, 17u); tf_round(x0, x1, 29u); tf_round(x0, x1, 16u); tf_round(x0, x1, 24u);
  x0 += ks2; x1 += k0 + 2u;
  tf_round(x0, x1, 13u); tf_round(x0, x1, 15u); tf_round(x0, x1, 26u); tf_round(x0, x1, 6u);
  x0 += k0;  x1 += k1 + 3u;
  tf_round(x0, x1, 17u); tf_round(x0, x1, 29u); tf_round(x0, x1, 16u); tf_round(x0, x1, 24u);
  x0 += k1;  x1 += ks2 + 4u;
  tf_round(x0, x1, 13u); tf_round(x0, x1, 15u); tf_round(x0, x1, 26u); tf_round(x0, x1, 6u);
  x0 += ks2; x1 += k0 + 5u;
  KeyPair r; r.a = x0; r.b = x1; return r;
}

__device__ __forceinline__ uint32_t sortkey(KeyPair S, uint32_t i) {
  KeyPair r = threefry(S.a, S.b, 0u, i);   // counter = 64-bit iota (hi=0,lo=i)
  return r.a ^ r.b;                        // 32-bit path XOR-folds the block
}

__device__ __forceinline__ void derive_keys(int b, KeyPair& S1, KeyPair& S2) {
  KeyPair root; root.a = 0u; root.b = 42u;
  KeyPair kb = threefry(root.a, root.b, 0u, (uint32_t)b);   // foldlike split
  KeyPair K1 = threefry(kb.a, kb.b, 0u, 0u);
  S1 = threefry(kb.a, kb.b, 0u, 1u);                        // round-1 subkey
  S2 = threefry(K1.a, K1.b, 0u, 1u);                        // round-2 subkey
}

#define T2VAL 27394240u  // ~2^32*320/NPIX

// ---- agent-scope per-address coherent accessors (bypass stale L1/L2) ------
__device__ __forceinline__ uint32_t ald_u32(const uint32_t* p) {
  return __hip_atomic_load(p, __ATOMIC_RELAXED, __HIP_MEMORY_SCOPE_AGENT);
}
__device__ __forceinline__ void ast_f64(double* p, double v) {
  __hip_atomic_store(p, v, __ATOMIC_RELAXED, __HIP_MEMORY_SCOPE_AGENT);
}
__device__ __forceinline__ double ald_f64(const double* p) {
  return __hip_atomic_load(p, __ATOMIC_RELAXED, __HIP_MEMORY_SCOPE_AGENT);
}

// ---- per-batch barriers (8 participants = the 8 chunk-blocks of batch b) --
// Slot: bar + b*4 u32. Monotonic arrival counter (zeroed at launch); each
// block keeps local phase ph; barrier #ph completes when count >= 8*ph.

// Full barrier (init phases): release fence (wbl2) before arrival, acquire
// fence (buffer_inv) on exit -> plain loads/stores safe across it.
__device__ __forceinline__ void bbar_full(uint32_t* bar, int b, int& ph) {
  __syncthreads();
  if (threadIdx.x == 0) {
    uint32_t* slot = bar + (b << 2);
    ph += 1;
    const uint32_t tgt = (uint32_t)(ph << 3);
    __builtin_amdgcn_fence(__ATOMIC_RELEASE, "agent");  // wbl2: publish writes
    __hip_atomic_fetch_add(slot, 1u, __ATOMIC_RELEASE, __HIP_MEMORY_SCOPE_AGENT);
    while (__hip_atomic_load(slot, __ATOMIC_RELAXED,
                             __HIP_MEMORY_SCOPE_AGENT) < tgt)
      __builtin_amdgcn_s_sleep(4);
    __builtin_amdgcn_fence(__ATOMIC_ACQUIRE, "agent");  // buffer_inv (once)
  }
  __syncthreads();
}

// Light barrier (k-means loop): release-only arrival, relaxed spin, NO
// acquire (keeps caches warm). Cross-block data after this barrier MUST
// use agent atomic ld/st (ald/ast/atomicAdd).
__device__ __forceinline__ void bbar_light(uint32_t* bar, int b, int& ph) {
  __syncthreads();
  if (threadIdx.x == 0) {
    uint32_t* slot = bar + (b << 2);
    ph += 1;
    const uint32_t tgt = (uint32_t)(ph << 3);
    __hip_atomic_fetch_add(slot, 1u, __ATOMIC_RELEASE, __HIP_MEMORY_SCOPE_AGENT);
    while (__hip_atomic_load(slot, __ATOMIC_RELAXED,
                             __HIP_MEMORY_SCOPE_AGENT) < tgt)
      __builtin_amdgcn_s_sleep(4);
    // no acquire fence
  }
  __syncthreads();
}

union SMem {
  struct { uint32_t lh[HBINS]; } p1;
  struct { u64 sc[CANDCAP]; uint32_t sh[HBINS]; uint32_t S[HBINS];
           uint32_t ts[256]; uint32_t Rt[NK]; } p2;
  struct { uint32_t bs[NK]; } p3;
  struct { u64 lc[NK * COLLCAP]; int jsel[NK]; } p4;
  // 68 KB: thread t owns accf[t*68 .. t*68+63] = 16 clusters x {c0,c1,c2,cnt}
  // (+4 pad floats for bank spread). Vector b128 RMW per quad; bank =
  // (4t + 4k + c)%32 -> 8 dwords/bank for wave64 b128 = conflict-free min.
  struct { float accf[256 * TSTRIDE]; } p5;
};

// compute one stage from named regs; vectorized accumulate (R14):
// one ds_read_b128 + 4 v_add + one ds_write_b128 per quad. Per-address
// f32 add order identical to the 4-scalar-RMW form (distinct addresses).
#define COMPQ(A_, B_, C_) do {                                                \
      const float qx[4][3] = {{A_.x, A_.y, A_.z}, {A_.w, B_.x, B_.y},         \
                              {B_.z, B_.w, C_.x}, {C_.y, C_.z, C_.w}};        \
      _Pragma("unroll")                                                       \
      for (int q = 0; q < 4; ++q) {                                           \
        const float v0 = qx[q][0], v1 = qx[q][1], v2 = qx[q][2];              \
        int best = 0;                                                         \
        float bd = 3.402823466e38f;                                           \
        _Pragma("unroll")                                                     \
        for (int k = 0; k < NK; ++k) {  /* _rn chain, strict <, asc. k */     \
          float d0 = __fsub_rn(v0, cr[3 * k + 0]);                            \
          float d1 = __fsub_rn(v1, cr[3 * k + 1]);                            \
          float d2 = __fsub_rn(v2, cr[3 * k + 2]);                            \
          float d = __fadd_rn(__fadd_rn(__fmul_rn(d0, d0), __fmul_rn(d1, d1)),\
                              __fmul_rn(d2, d2));                             \
          bool cnd = d < bd;                                                  \
          bd = cnd ? d : bd;                                                  \
          best = cnd ? k : best;                                              \
        }                                                                     \
        if (kn >= 0) best = kn;        /* np.argmin: first NaN wins */        \
        float4* pacc = (float4*)&a0[best << 2];                               \
        float4 o = *pacc;                                                     \
        o.x += v0; o.y += v1; o.z += v2; o.w += 1.0f;                         \
        *pacc = o;                                                            \
      }                                                                       \
    } while (0)

__global__ __launch_bounds__(256, 2) void mega(
    const float* __restrict__ x, float* __restrict__ out,
    float* __restrict__ cent, double* __restrict__ sums,
    uint32_t* __restrict__ ncand, uint32_t* __restrict__ ncoll,
    uint32_t* __restrict__ bar, uint32_t* __restrict__ hist,
    uint32_t* __restrict__ binsel, uint32_t* __restrict__ rem,
    u64* __restrict__ cand, u64* __restrict__ coll) {
  __shared__ SMem sm;
  const int blk = (int)blockIdx.x;
  const int tid = (int)threadIdx.x;
  const int b = blk >> 3;        // batch
  const int c = blk & 7;         // chunk within batch
  int ph = 0;                    // per-batch barrier phase (used by tid 0)

  KeyPair S1, S2;
  derive_keys(b, S1, S2);

  // ---- P1: key2 candidate filter + key1 prefix histogram ----
  for (int i = tid; i < HBINS; i += 256) sm.p1.lh[i] = 0u;
  __syncthreads();
  {
    const int start = c * CHUNK;
    for (int i = start + tid; i < start + CHUNK; i += 256) {
      uint32_t k2 = sortkey(S2, (uint32_t)i);
      if (k2 < T2VAL) {
        uint32_t p = atomicAdd(&ncand[b], 1u);
        if (p < CANDCAP) cand[b * CANDCAP + p] = ((u64)k2 << 32) | (uint32_t)i;
      }
      uint32_t k1 = sortkey(S1, (uint32_t)i);
      atomicAdd(&sm.p1.lh[k1 >> 21], 1u);
    }
    __syncthreads();
    for (int i = tid; i < HBINS; i += 256)
      if (sm.p1.lh[i]) atomicAdd(&hist[b * HBINS + i], sm.p1.lh[i]);
  }
  bbar_full(bar, b, ph);

  // ---- P2 (chunk-0 block of each batch): rank candidates, scan hist,
  //      binary search ----
  if (c == 0) {
    const int bb = b;
    uint32_t nc = ald_u32(&ncand[bb]);   // uniform addr: keep atomic load
    const int M = nc < CANDCAP ? (int)nc : CANDCAP;
    for (int i = tid; i < M; i += 256) sm.p2.sc[i] = cand[bb * CANDCAP + i];
    for (int i = tid; i < HBINS; i += 256) sm.p2.sh[i] = hist[bb * HBINS + i];
    __syncthreads();
    // top-16 rank under (key2, idx); distinct pairs -> unique ranks
    for (int j = tid; j < M; j += 256) {
      u64 me = sm.p2.sc[j];
      int r = 0;
      for (int t = 0; t < M; ++t) r += (sm.p2.sc[t] < me) ? 1 : 0;
      if (r < NK) sm.p2.Rt[r] = (uint32_t)(me & 0xffffffffu);
    }
    // parallel inclusive scan of sh -> S (8 bins/thread + block scan)
    uint32_t loc[8]; uint32_t run = 0;
    for (int j = 0; j < 8; ++j) { run += sm.p2.sh[tid * 8 + j]; loc[j] = run; }
    sm.p2.ts[tid] = run;
    __syncthreads();
    for (int off = 1; off < 256; off <<= 1) {
      uint32_t v = (tid >= off) ? sm.p2.ts[tid - off] : 0u;
      __syncthreads();
      sm.p2.ts[tid] += v;
      __syncthreads();
    }
    uint32_t excl = sm.p2.ts[tid] - run;
    for (int j = 0; j < 8; ++j) sm.p2.S[tid * 8 + j] = excl + loc[j];
    __syncthreads();
    if (tid < NK) {
      uint32_t R = sm.p2.Rt[tid];
      int lo = 0, hi = HBINS - 1;
      while (lo < hi) {                      // smallest i with S[i] > R
        int mid = (lo + hi) >> 1;
        if (sm.p2.S[mid] > R) hi = mid; else lo = mid + 1;
      }
      binsel[bb * NK + tid] = (uint32_t)lo;
      rem[bb * NK + tid] = R - (lo ? sm.p2.S[lo - 1] : 0u);
    }
  }
  bbar_full(bar, b, ph);

  // ---- P3: collect key1 elements landing in each target's bin ----
  {
    __shared__ uint32_t bs_s[NK];
    if (tid < NK) bs_s[tid] = binsel[b * NK + tid];
    __syncthreads();
    const int start = c * CHUNK;
    for (int i = start + tid; i < start + CHUNK; i += 256) {
      uint32_t k1 = sortkey(S1, (uint32_t)i);
      uint32_t pb = k1 >> 21;
      #pragma unroll
      for (int t = 0; t < NK; ++t) {
        if (pb == bs_s[t]) {
          uint32_t p = atomicAdd(&ncoll[b * NK + t], 1u);
          if (p < COLLCAP)
            coll[(b * NK + t) * COLLCAP + p] = ((u64)k1 << 32) | (uint32_t)i;
        }
      }
    }
  }
  bbar_full(bar, b, ph);

  // ---- P4 (chunk-0 block of each batch): stable rank-select, gather cent --
  if (c == 0) {
    const int bb = b;
    for (int i = tid; i < NK * COLLCAP; i += 256)
      sm.p4.lc[i] = coll[bb * NK * COLLCAP + i];
    __syncthreads();
    if (tid < NK) {
      uint32_t ncl = ncoll[bb * NK + tid];
      const int m = ncl < COLLCAP ? (int)ncl : COLLCAP;
      const uint32_t r = rem[bb * NK + tid];
      const u64* cc = &sm.p4.lc[tid * COLLCAP];
      u64 lo = 0ULL, cur = ~0ULL;
      bool first = true;
      for (uint32_t pass = 0; pass <= r; ++pass) {
        cur = ~0ULL;
        for (int i = 0; i < m; ++i) {
          u64 v = cc[i];
          if ((first || v > lo) && v < cur) cur = v;
        }
        lo = cur; first = false;
      }
      sm.p4.jsel[tid] = (int)(cur & 0xffffffffu);
    }
    __syncthreads();
    if (tid < NK * NCH) {
      int k = tid / NCH, ch = tid % NCH;
      cent[bb * NK * NCH + tid] =
          x[((size_t)bb * NPIX + (size_t)sm.p4.jsel[k]) * NCH + ch];
    }
  }
  bbar_full(bar, b, ph);

  // ---- P5: 10 k-means iterations, 1 LIGHT per-batch barrier each ----
  // All cross-block traffic via agent atomic ld/st + HW atomicAdd.
  const float4* px4 = (const float4*)(x + (size_t)b * NPIX * NCH + (size_t)c * (CHUNK * NCH));
  float* accf = sm.p5.accf;

  for (int it = 0; it < NITER; ++it) {
    // (1) new centroids -> accf[0..47] scratch (redundant per block)
    if (tid < NK * NCH) {
      float v;
      if (it == 0) {
        v = cent[b * NK * NCH + tid];
      } else {
        const int k = tid / NCH, ch = tid - k * NCH;
        double* sb = &sums[((it - 1) % 3) * (NB * NK * 4) + b * NK * 4];
        double s = ald_f64(&sb[k * 4 + ch]);
        double n = ald_f64(&sb[k * 4 + 3]);
        v = (float)(s / n);                  // 0/0 -> NaN, matching reference
      }
      accf[tid] = v;
    }
    __syncthreads();
    // (2) broadcast to registers; knan per-thread (batch-uniform result)
    float cr[NK * NCH];
    {
      const float4* cp = (const float4*)accf;
      #pragma unroll
      for (int i = 0; i < 12; ++i) {
        float4 t4 = cp[i];
        cr[4 * i + 0] = t4.x; cr[4 * i + 1] = t4.y;
        cr[4 * i + 2] = t4.z; cr[4 * i + 3] = t4.w;
      }
    }
    int kn = -1;
    #pragma unroll
    for (int k = NK - 1; k >= 0; --k) {      // descending so lowest k wins
      float a = cr[3 * k], bb2 = cr[3 * k + 1], cc2 = cr[3 * k + 2];
      if (a != a || bb2 != bb2 || cc2 != cc2) kn = k;
    }
    __syncthreads();
    // (3) zero accf (256*68 floats = 4352 float4) + next-parity global buf
    {
      float4 z4 = make_float4(0.f, 0.f, 0.f, 0.f);
      float4* zp = (float4*)accf;
      #pragma unroll
      for (int i = 0; i < 17; ++i) zp[tid + 256 * i] = z4;
      if (tid < NK * 4)
        ast_f64(&sums[((it + 1) % 3) * (NB * NK * 4) + b * NK * 4 + tid], 0.0);
    }
    __syncthreads();
    // (4) pixel loop: rolled 1-ahead register pipeline (R13) + vectorized
    // b128 accumulate (R14). Same per-thread j order and per-address f32
    // add order as R7/R13 -> identical f32 partials.
    {
      float* a0 = &accf[tid * TSTRIDE];
      float4 A = px4[3 * tid], B = px4[3 * tid + 1], C = px4[3 * tid + 2];
      float4 An = make_float4(0.f, 0.f, 0.f, 0.f);
      float4 Bn = An, Cn = An;
      #pragma unroll 1
      for (int j = tid; j < NQUADS; j += 256) {
        const int jn = j + 256;
        if (jn < NQUADS) {                 // prefetch next stage
          An = px4[3 * jn]; Bn = px4[3 * jn + 1]; Cn = px4[3 * jn + 2];
        }
        COMPQ(A, B, C);
        A = An; B = Bn; C = Cn;
      }
    }
    __syncthreads();
    // (5) reduce: thread (r=tid&63, q=tid>>6) sums the same logical
    // elements in the same rotated f64 order as R13, re-addressed for the
    // [tid][68] layout: column t's value for row r lives at accf[t*68+r].
    double part = 0.0;
    {
      const int r = tid & 63, q = tid >> 6;
      const int s0 = r & 15;
      #pragma unroll
      for (int m = 0; m < 16; ++m) {
        const int c0 = q * 64 + (((m + s0) & 15) << 2);
        part += (double)accf[(c0 + 0) * TSTRIDE + r];
        part += (double)accf[(c0 + 1) * TSTRIDE + r];
        part += (double)accf[(c0 + 2) * TSTRIDE + r];
        part += (double)accf[(c0 + 3) * TSTRIDE + r];
      }
    }
    __syncthreads();
    {
      double* red = (double*)accf;       // reuse low 2KB as f64 scratch
      red[tid] = part;
      __syncthreads();
      if (tid < 64) {
        double tot = red[tid] + red[64 + tid] + red[128 + tid] + red[192 + tid];
        atomicAdd(&sums[(it % 3) * (NB * NK * 4) + b * NK * 4 + tid], tot);
      }
    }
    bbar_light(bar, b, ph);
  }

  // final centroids -> out (chunk-0 blocks write; coherent reads)
  if (c == 0 && tid < NK * NCH) {
    const int k = tid / NCH, ch = tid - k * NCH;
    double* sb = &sums[((NITER - 1) % 3) * (NB * NK * 4) + b * NK * 4];
    out[b * NK * NCH + tid] = (float)(ald_f64(&sb[k * 4 + ch]) /
                                      ald_f64(&sb[k * 4 + 3]));
  }
}

// ---------------------------------------------------------------------------
// Fallback path (ws too small): R1-verified monolithic kinit + R2 loop.
// ---------------------------------------------------------------------------
__global__ __launch_bounds__(256) void kinit_mono(const float* __restrict__ x,
                                                  float* __restrict__ cent,
                                                  float* __restrict__ sums) {
  const int b = (int)blockIdx.x;
  const int tid = (int)threadIdx.x;
  __shared__ u64 cand[CANDCAP];
  __shared__ u64 coll[NK][COLLCAP];
  __shared__ uint32_t hist[HBINS];
  __shared__ uint32_t Rtgt[NK];
  __shared__ uint32_t binsel[NK];
  __shared__ uint32_t rem[NK];
  __shared__ int jsel[NK];
  __shared__ int ncand;
  __shared__ int ncoll[NK];
  KeyPair S1, S2;
  derive_keys(b, S1, S2);
  if (tid == 0) ncand = 0;
  if (tid < NK) ncoll[tid] = 0;
  for (int i = tid; i < HBINS; i += 256) hist[i] = 0u;
  __syncthreads();
  for (int i = tid; i < NPIX; i += 256) {
    uint32_t k2 = sortkey(S2, (uint32_t)i);
    if (k2 < T2VAL) {
      int p = atomicAdd(&ncand, 1);
      if (p < CANDCAP) cand[p] = ((u64)k2 << 32) | (uint32_t)i;
    }
    uint32_t k1 = sortkey(S1, (uint32_t)i);
    atomicAdd(&hist[k1 >> 21], 1u);
  }
  __syncthreads();
  const int M = ncand < CANDCAP ? ncand : CANDCAP;
  for (int j = tid; j < M; j += 256) {
    u64 me = cand[j];
    int rank = 0;
    for (int t = 0; t < M; ++t) rank += (cand[t] < me) ? 1 : 0;
    if (rank < NK) Rtgt[rank] = (uint32_t)(me & 0xffffffffu);
  }
  __syncthreads();
  if (tid < NK) {
    uint32_t R = Rtgt[tid], cum = 0u, bin = 0u;
    for (int i = 0; i < HBINS; ++i) {
      uint32_t h = hist[i];
      if (R < cum + h) { bin = (uint32_t)i; break; }
      cum += h;
    }
    binsel[tid] = bin;
    rem[tid] = R - cum;
  }
  __syncthreads();
  for (int i = tid; i < NPIX; i += 256) {
    uint32_t k1 = sortkey(S1, (uint32_t)i);
    uint32_t pb = k1 >> 21;
    #pragma unroll
    for (int t = 0; t < NK; ++t) {
      if (pb == binsel[t]) {
        int p = atomicAdd(&ncoll[t], 1);
        if (p < COLLCAP) coll[t][p] = ((u64)k1 << 32) | (uint32_t)i;
      }
    }
  }
  __syncthreads();
  if (tid < NK) {
    int m = ncoll[tid] < COLLCAP ? ncoll[tid] : COLLCAP;
    uint32_t r = rem[tid];
    u64 lo = 0ULL, cur = ~0ULL;
    bool first = true;
    for (uint32_t pass = 0; pass <= r; ++pass) {
      cur = ~0ULL;
      for (int t = 0; t < m; ++t) {
        u64 v = coll[tid][t];
        if ((first || v > lo) && v < cur) cur = v;
      }
      lo = cur; first = false;
    }
    jsel[tid] = (int)(cur & 0xffffffffu);
  }
  __syncthreads();
  if (tid < NK * NCH) {
    int k = tid / NCH, c = tid % NCH;
    cent[(b * NK + k) * NCH + c] = x[((size_t)b * NPIX + (size_t)jsel[k]) * NCH + c];
  }
  if (tid < NK * 4) sums[b * NK * 4 + tid] = 0.0f;
}

__global__ __launch_bounds__(256) void kassign(const float* __restrict__ x,
                                               const float* __restrict__ cent,
                                               float* __restrict__ sums) {
  const int b = (int)blockIdx.y;
  const int tid = (int)threadIdx.x;
  __shared__ float cs[NK * NCH];
  __shared__ float acc[4][NK * 4];
  __shared__ int knan_s;
  if (tid < NK * NCH) cs[tid] = cent[b * NK * NCH + tid];
  acc[tid >> 6][tid & 63] = 0.0f;
  __syncthreads();
  if (tid == 0) {
    int kn = -1;
    for (int k = 0; k < NK; ++k) {
      float a = cs[3 * k], bb = cs[3 * k + 1], cc = cs[3 * k + 2];
      if (a != a || bb != bb || cc != cc) { kn = k; break; }
    }
    knan_s = kn;
  }
  __syncthreads();
  float cr[NK * NCH];
  #pragma unroll
  for (int i = 0; i < NK * NCH; ++i) cr[i] = cs[i];
  const float* xb = x + (size_t)b * NPIX * NCH;
  const float4* p = (const float4*)(xb + (size_t)blockIdx.x * 3072);
  const float4 A = p[3 * tid], Bv = p[3 * tid + 1], Cv = p[3 * tid + 2];
  const float px[4][3] = {{A.x, A.y, A.z}, {A.w, Bv.x, Bv.y},
                          {Bv.z, Bv.w, Cv.x}, {Cv.y, Cv.z, Cv.w}};
  float* a0 = acc[tid >> 6];
  const int kn = knan_s;
  #pragma unroll
  for (int q = 0; q < 4; ++q) {
    const float v0 = px[q][0], v1 = px[q][1], v2 = px[q][2];
    int best = 0;
    float bd = 3.402823466e38f;
    #pragma unroll
    for (int k = 0; k < NK; ++k) {
      float d0 = __fsub_rn(v0, cr[3 * k + 0]);
      float d1 = __fsub_rn(v1, cr[3 * k + 1]);
      float d2 = __fsub_rn(v2, cr[3 * k + 2]);
      float d = __fadd_rn(__fadd_rn(__fmul_rn(d0, d0), __fmul_rn(d1, d1)),
                          __fmul_rn(d2, d2));
      bool cnd = d < bd;
      bd = cnd ? d : bd;
      best = cnd ? k : best;
    }
    if (kn >= 0) best = kn;
    atomicAdd(&a0[best * 4 + 0], v0);
    atomicAdd(&a0[best * 4 + 1], v1);
    atomicAdd(&a0[best * 4 + 2], v2);
    atomicAdd(&a0[best * 4 + 3], 1.0f);
  }
  __syncthreads();
  if (tid < NK * 4) {
    float v = acc[0][tid] + acc[1][tid] + acc[2][tid] + acc[3][tid];
    atomicAdd(&sums[b * NK * 4 + tid], v);
  }
}

__global__ __launch_bounds__(64) void kupdate(float* __restrict__ cent,
                                              float* __restrict__ sums,
                                              float* __restrict__ out) {
  const int b = (int)blockIdx.x;
  const int t = (int)threadIdx.x;
  float v = 0.0f;
  if (t < NK * NCH) {
    const int k = t / NCH, c = t % NCH;
    v = sums[b * NK * 4 + k * 4 + c] / sums[b * NK * 4 + k * 4 + 3];
  }
  __syncthreads();
  if (t < NK * NCH) {
    cent[b * NK * NCH + t] = v;
    out[b * NK * NCH + t] = v;
  }
  sums[b * NK * 4 + t] = 0.0f;
}

extern "C" void kernel_launch(void* const* d_in, const int* in_sizes, int n_in,
                              void* d_out, int out_size, void* d_ws, size_t ws_size,
                              hipStream_t stream) {
  (void)in_sizes; (void)n_in; (void)out_size;
  const float* x = (const float*)d_in[0];
  float* out = (float*)d_out;
  char* ws = (char*)d_ws;

  // ws layout (bytes)
  float*    cent   = (float*)(ws + 0);              // 12288
  double*   sums   = (double*)(ws + 12288);         // 98304 (3 parity bufs)
  uint32_t* ncand  = (uint32_t*)(ws + 110592);      // 256    } zero
  uint32_t* ncoll  = (uint32_t*)(ws + 110848);      // 4096   } zone
  uint32_t* bar    = (uint32_t*)(ws + 114944);      // 1024   } 110592..
  uint32_t* hist   = (uint32_t*)(ws + 115968);      // 524288 } ..640256
  uint32_t* binsel = (uint32_t*)(ws + 640256);      // 4096
  uint32_t* rem    = (uint32_t*)(ws + 644352);      // 4096
  u64*      cand   = (u64*)(ws + 648448);           // 524288
  u64*      coll   = (u64*)(ws + 1172736);          // 1048576
  const size_t REQ = 2221312;

  if (ws_size >= REQ) {
    hipMemsetAsync(ws + 110592, 0, 529664, stream);
    mega<<<NBLK, 256, 0, stream>>>(x, out, cent, sums, ncand, ncoll, bar,
                                   hist, binsel, rem, cand, coll);
  } else {
    float* centf = (float*)ws;                 // fallback: f32 sums layout
    float* sumsf = centf + NB * NK * NCH;
    kinit_mono<<<NB, 256, 0, stream>>>(x, centf, sumsf);
    for (int it = 0; it < NITER; ++it) {
      kassign<<<dim3(49, NB), 256, 0, stream>>>(x, centf, sumsf);
      kupdate<<<NB, 64, 0, stream>>>(centf, sumsf, out);
    }
  }
}

// Round 16
// 480.999 us; speedup vs baseline: 1.0010x; 1.0010x over previous
//
#include <hip/hip_runtime.h>
#include <stdint.h>

// ---------------------------------------------------------------------------
// ColorExtractor: per-image k-means (B=64, H*W=50176, C=3, K=16, 10 iters).
// Threefry2x32 bit-exact (verified R1, absmax 0.0).
// R15: exploit column privacy of the R14 layout to cut 2 of 6 per-iter
// __syncthreads. R14 (b128 accumulate) was NEUTRAL vs R13 (both ~434us
// median; bank-conflict counter 20x up but absorbed) -> LDS accumulate is
// NOT the critical path. VALUBusy*dur ~150us invariant for 3 rounds; the
// ~280us idle is sync/barrier overhead + frozen tail imbalance.
// Changes vs R14 (structure only, zero numerics impact):
//  (a) centroid staging moved from accf[0..47] (= thread 0's column!) to a
//      separate crbuf[48] -> the (2)->(3) anti-dependency sync disappears.
//  (b) accf zeroing: each thread zeros its OWN contiguous column (17 b128)
//      instead of cooperative strided zeroing -> no sync before the pixel
//      loop (same-thread LDS in-order).
//  Per-iter chain: (1) stage crbuf | sync | (2) read crbuf+knan, self-zero,
//  ast_f64 | (4) pixel loop | sync | (5) reduce | sync | red write | sync |
//  atomicAdd | light barrier  == 4 syncs (was 6).
// Config (locked by R7-R14 map): launch_bounds(256,2) = 128-VGPR cap +
// 2 blk/CU; rolled 1-ahead pipeline fits at 88 VGPR, no spill.
// Numerics-critical invariants (DO NOT CHANGE): pixel->thread partition
// (8 chunks x 256 threads, j stride 256 ascending), per-thread per-address
// f32 add order, f64 column reduce order, _rn chain, first-NaN argmin.
// R7 kept: per-batch 8-block barriers (monotonic counter), release-only
// light barriers + agent atomics in the loop, full acq/rel in init.
// ---------------------------------------------------------------------------

#define NB    64
#define NPIX  50176
#define NK    16
#define NCH   3
#define NITER 10
#define HBINS 2048
#define CANDCAP 1024     // expect ~320 cands/batch (T2VAL), huge margin
#define COLLCAP 128      // expect ~24.5/bin
#define NBLK  512        // 8 chunks x 64 batches; 2 blocks/CU on 256 CUs
#define CHUNK (NPIX / 8) // 6272 px per block-chunk
#define NQUADS (CHUNK / 4)  // 1568 = 6*256 + 32
#define TSTRIDE 68       // per-thread accf stride: 16*4 + 4 pad (bank spread)

typedef unsigned long long u64;

struct KeyPair { uint32_t a, b; };

__device__ __forceinline__ uint32_t rotl32(uint32_t v, uint32_t r) {
  return (v << r) | (v >> (32u - r));
}
__device__ __forceinline__ void tf_round(uint32_t& x0, uint32_t& x1, uint32_t r) {
  x0 += x1; x1 = rotl32(x1, r); x1 ^= x0;
}

// Threefry-2x32, 20 rounds, exactly as jax/_src/prng.py lowering.
__device__ __forceinline__ KeyPair threefry(uint32_t k0, uint32_t k1,
                                            uint32_t x0, uint32_t x1) {
  const uint32_t ks2 = k0 ^ k1 ^ 0x1BD11BDAu;
  x0 += k0; x1 += k1;
  tf_round(x0, x1, 13u); tf_round(x0, x1, 15u); tf_round(x0, x1, 26u); tf_round(x0, x1, 6u);
  x0 += k1;  x1 += ks2 + 1u;
  tf_round(x0, x1, 17u); tf_round(x0, x1, 29u); tf_round(x0, x1, 16u); tf_round(x0, x1, 24u);
  x0 += ks2; x1 += k0 + 2u;
  tf_round(x0, x1, 13u); tf_round(x0, x1, 15u); tf_round(x0, x1, 26u); tf_round(x0, x1, 6u);
  x0 += k0;  x1 += k1 + 3u;
  tf_round(x0, x1, 17u); tf_round(x0, x1, 29u); tf_round(x0, x1, 16u); tf_round(x0, x1, 24u);
  x0 += k1;  x1 += ks2 + 4u;
  tf_round(x0, x1, 13u); tf_round(x0, x1, 15u); tf_round(x0, x1, 26u); tf_round(x0, x1, 6u);
  x0 += ks2; x1 += k0 + 5u;
  KeyPair r; r.a = x0; r.b = x1; return r;
}

__device__ __forceinline__ uint32_t sortkey(KeyPair S, uint32_t i) {
  KeyPair r = threefry(S.a, S.b, 0u, i);   // counter = 64-bit iota (hi=0,lo=i)
  return r.a ^ r.b;                        // 32-bit path XOR-folds the block
}

__device__ __forceinline__ void derive_keys(int b, KeyPair& S1, KeyPair& S2) {
  KeyPair root; root.a = 0u; root.b = 42u;
  KeyPair kb = threefry(root.a, root.b, 0u, (uint32_t)b);   // foldlike split
  KeyPair K1 = threefry(kb.a, kb.b, 0u, 0u);
  S1 = threefry(kb.a, kb.b, 0u, 1u);                        // round-1 subkey
  S2 = threefry(K1.a, K1.b, 0u, 1u);                        // round-2 subkey
}

#define T2VAL 27394240u  // ~2^32*320/NPIX

// ---- agent-scope per-address coherent accessors (bypass stale L1/L2) ------
__device__ __forceinline__ uint32_t ald_u32(const uint32_t* p) {
  return __hip_atomic_load(p, __ATOMIC_RELAXED, __HIP_MEMORY_SCOPE_AGENT);
}
__device__ __forceinline__ void ast_f64(double* p, double v) {
  __hip_atomic_store(p, v, __ATOMIC_RELAXED, __HIP_MEMORY_SCOPE_AGENT);
}
__device__ __forceinline__ double ald_f64(const double* p) {
  return __hip_atomic_load(p, __ATOMIC_RELAXED, __HIP_MEMORY_SCOPE_AGENT);
}

// ---- per-batch barriers (8 participants = the 8 chunk-blocks of batch b) --
// Slot: bar + b*4 u32. Monotonic arrival counter (zeroed at launch); each
// block keeps local phase ph; barrier #ph completes when count >= 8*ph.

// Full barrier (init phases): release fence (wbl2) before arrival, acquire
// fence (buffer_inv) on exit -> plain loads/stores safe across it.
__device__ __forceinline__ void bbar_full(uint32_t* bar, int b, int& ph) {
  __syncthreads();
  if (threadIdx.x == 0) {
    uint32_t* slot = bar + (b << 2);
    ph += 1;
    const uint32_t tgt = (uint32_t)(ph << 3);
    __builtin_amdgcn_fence(__ATOMIC_RELEASE, "agent");  // wbl2: publish writes
    __hip_atomic_fetch_add(slot, 1u, __ATOMIC_RELEASE, __HIP_MEMORY_SCOPE_AGENT);
    while (__hip_atomic_load(slot, __ATOMIC_RELAXED,
                             __HIP_MEMORY_SCOPE_AGENT) < tgt)
      __builtin_amdgcn_s_sleep(4);
    __builtin_amdgcn_fence(__ATOMIC_ACQUIRE, "agent");  // buffer_inv (once)
  }
  __syncthreads();
}

// Light barrier (k-means loop): release-only arrival, relaxed spin, NO
// acquire (keeps caches warm). Cross-block data after this barrier MUST
// use agent atomic ld/st (ald/ast/atomicAdd).
__device__ __forceinline__ void bbar_light(uint32_t* bar, int b, int& ph) {
  __syncthreads();
  if (threadIdx.x == 0) {
    uint32_t* slot = bar + (b << 2);
    ph += 1;
    const uint32_t tgt = (uint32_t)(ph << 3);
    __hip_atomic_fetch_add(slot, 1u, __ATOMIC_RELEASE, __HIP_MEMORY_SCOPE_AGENT);
    while (__hip_atomic_load(slot, __ATOMIC_RELAXED,
                             __HIP_MEMORY_SCOPE_AGENT) < tgt)
      __builtin_amdgcn_s_sleep(4);
    // no acquire fence
  }
  __syncthreads();
}

union SMem {
  struct { uint32_t lh[HBINS]; } p1;
  struct { u64 sc[CANDCAP]; uint32_t sh[HBINS]; uint32_t S[HBINS];
           uint32_t ts[256]; uint32_t Rt[NK]; } p2;
  struct { uint32_t bs[NK]; } p3;
  struct { u64 lc[NK * COLLCAP]; int jsel[NK]; } p4;
  // ~70 KB: thread t owns accf[t*68 .. t*68+63] (16 clusters x
  // {c0,c1,c2,cnt} + 4 pad). crbuf is SEPARATE so centroid staging never
  // aliases thread 0's column -> fewer syncs (R15).
  struct { float accf[256 * TSTRIDE]; float crbuf[48]; } p5;
};

// compute one stage from named regs; vectorized b128 accumulate (R14).
// Per-address f32 add order identical to the scalar-RMW form.
#define COMPQ(A_, B_, C_) do {                                                \
      const float qx[4][3] = {{A_.x, A_.y, A_.z}, {A_.w, B_.x, B_.y},         \
                              {B_.z, B_.w, C_.x}, {C_.y, C_.z, C_.w}};        \
      _Pragma("unroll")                                                       \
      for (int q = 0; q < 4; ++q) {                                           \
        const float v0 = qx[q][0], v1 = qx[q][1], v2 = qx[q][2];              \
        int best = 0;                                                         \
        float bd = 3.402823466e38f;                                           \
        _Pragma("unroll")                                                     \
        for (int k = 0; k < NK; ++k) {  /* _rn chain, strict <, asc. k */     \
          float d0 = __fsub_rn(v0, cr[3 * k + 0]);                            \
          float d1 = __fsub_rn(v1, cr[3 * k + 1]);                            \
          float d2 = __fsub_rn(v2, cr[3 * k + 2]);                            \
          float d = __fadd_rn(__fadd_rn(__fmul_rn(d0, d0), __fmul_rn(d1, d1)),\
                              __fmul_rn(d2, d2));                             \
          bool cnd = d < bd;                                                  \
          bd = cnd ? d : bd;                                                  \
          best = cnd ? k : best;                                              \
        }                                                                     \
        if (kn >= 0) best = kn;        /* np.argmin: first NaN wins */        \
        float4* pacc = (float4*)&a0[best << 2];                               \
        float4 o = *pacc;                                                     \
        o.x += v0; o.y += v1; o.z += v2; o.w += 1.0f;                         \
        *pacc = o;                                                            \
      }                                                                       \
    } while (0)

__global__ __launch_bounds__(256, 2) void mega(
    const float* __restrict__ x, float* __restrict__ out,
    float* __restrict__ cent, double* __restrict__ sums,
    uint32_t* __restrict__ ncand, uint32_t* __restrict__ ncoll,
    uint32_t* __restrict__ bar, uint32_t* __restrict__ hist,
    uint32_t* __restrict__ binsel, uint32_t* __restrict__ rem,
    u64* __restrict__ cand, u64* __restrict__ coll) {
  __shared__ SMem sm;
  const int blk = (int)blockIdx.x;
  const int tid = (int)threadIdx.x;
  const int b = blk >> 3;        // batch
  const int c = blk & 7;         // chunk within batch
  int ph = 0;                    // per-batch barrier phase (used by tid 0)

  KeyPair S1, S2;
  derive_keys(b, S1, S2);

  // ---- P1: key2 candidate filter + key1 prefix histogram ----
  for (int i = tid; i < HBINS; i += 256) sm.p1.lh[i] = 0u;
  __syncthreads();
  {
    const int start = c * CHUNK;
    for (int i = start + tid; i < start + CHUNK; i += 256) {
      uint32_t k2 = sortkey(S2, (uint32_t)i);
      if (k2 < T2VAL) {
        uint32_t p = atomicAdd(&ncand[b], 1u);
        if (p < CANDCAP) cand[b * CANDCAP + p] = ((u64)k2 << 32) | (uint32_t)i;
      }
      uint32_t k1 = sortkey(S1, (uint32_t)i);
      atomicAdd(&sm.p1.lh[k1 >> 21], 1u);
    }
    __syncthreads();
    for (int i = tid; i < HBINS; i += 256)
      if (sm.p1.lh[i]) atomicAdd(&hist[b * HBINS + i], sm.p1.lh[i]);
  }
  bbar_full(bar, b, ph);

  // ---- P2 (chunk-0 block of each batch): rank candidates, scan hist,
  //      binary search ----
  if (c == 0) {
    const int bb = b;
    uint32_t nc = ald_u32(&ncand[bb]);   // uniform addr: keep atomic load
    const int M = nc < CANDCAP ? (int)nc : CANDCAP;
    for (int i = tid; i < M; i += 256) sm.p2.sc[i] = cand[bb * CANDCAP + i];
    for (int i = tid; i < HBINS; i += 256) sm.p2.sh[i] = hist[bb * HBINS + i];
    __syncthreads();
    // top-16 rank under (key2, idx); distinct pairs -> unique ranks
    for (int j = tid; j < M; j += 256) {
      u64 me = sm.p2.sc[j];
      int r = 0;
      for (int t = 0; t < M; ++t) r += (sm.p2.sc[t] < me) ? 1 : 0;
      if (r < NK) sm.p2.Rt[r] = (uint32_t)(me & 0xffffffffu);
    }
    // parallel inclusive scan of sh -> S (8 bins/thread + block scan)
    uint32_t loc[8]; uint32_t run = 0;
    for (int j = 0; j < 8; ++j) { run += sm.p2.sh[tid * 8 + j]; loc[j] = run; }
    sm.p2.ts[tid] = run;
    __syncthreads();
    for (int off = 1; off < 256; off <<= 1) {
      uint32_t v = (tid >= off) ? sm.p2.ts[tid - off] : 0u;
      __syncthreads();
      sm.p2.ts[tid] += v;
      __syncthreads();
    }
    uint32_t excl = sm.p2.ts[tid] - run;
    for (int j = 0; j < 8; ++j) sm.p2.S[tid * 8 + j] = excl + loc[j];
    __syncthreads();
    if (tid < NK) {
      uint32_t R = sm.p2.Rt[tid];
      int lo = 0, hi = HBINS - 1;
      while (lo < hi) {                      // smallest i with S[i] > R
        int mid = (lo + hi) >> 1;
        if (sm.p2.S[mid] > R) hi = mid; else lo = mid + 1;
      }
      binsel[bb * NK + tid] = (uint32_t)lo;
      rem[bb * NK + tid] = R - (lo ? sm.p2.S[lo - 1] : 0u);
    }
  }
  bbar_full(bar, b, ph);

  // ---- P3: collect key1 elements landing in each target's bin ----
  {
    __shared__ uint32_t bs_s[NK];
    if (tid < NK) bs_s[tid] = binsel[b * NK + tid];
    __syncthreads();
    const int start = c * CHUNK;
    for (int i = start + tid; i < start + CHUNK; i += 256) {
      uint32_t k1 = sortkey(S1, (uint32_t)i);
      uint32_t pb = k1 >> 21;
      #pragma unroll
      for (int t = 0; t < NK; ++t) {
        if (pb == bs_s[t]) {
          uint32_t p = atomicAdd(&ncoll[b * NK + t], 1u);
          if (p < COLLCAP)
            coll[(b * NK + t) * COLLCAP + p] = ((u64)k1 << 32) | (uint32_t)i;
        }
      }
    }
  }
  bbar_full(bar, b, ph);

  // ---- P4 (chunk-0 block of each batch): stable rank-select, gather cent --
  if (c == 0) {
    const int bb = b;
    for (int i = tid; i < NK * COLLCAP; i += 256)
      sm.p4.lc[i] = coll[bb * NK * COLLCAP + i];
    __syncthreads();
    if (tid < NK) {
      uint32_t ncl = ncoll[bb * NK + tid];
      const int m = ncl < COLLCAP ? (int)ncl : COLLCAP;
      const uint32_t r = rem[bb * NK + tid];
      const u64* cc = &sm.p4.lc[tid * COLLCAP];
      u64 lo = 0ULL, cur = ~0ULL;
      bool first = true;
      for (uint32_t pass = 0; pass <= r; ++pass) {
        cur = ~0ULL;
        for (int i = 0; i < m; ++i) {
          u64 v = cc[i];
          if ((first || v > lo) && v < cur) cur = v;
        }
        lo = cur; first = false;
      }
      sm.p4.jsel[tid] = (int)(cur & 0xffffffffu);
    }
    __syncthreads();
    if (tid < NK * NCH) {
      int k = tid / NCH, ch = tid % NCH;
      cent[bb * NK * NCH + tid] =
          x[((size_t)bb * NPIX + (size_t)sm.p4.jsel[k]) * NCH + ch];
    }
  }
  bbar_full(bar, b, ph);

  // ---- P5: 10 k-means iterations, 1 LIGHT per-batch barrier each ----
  // All cross-block traffic via agent atomic ld/st + HW atomicAdd.
  const float4* px4 = (const float4*)(x + (size_t)b * NPIX * NCH + (size_t)c * (CHUNK * NCH));
  float* accf = sm.p5.accf;

  for (int it = 0; it < NITER; ++it) {
    // (1) new centroids -> crbuf (separate from accf -> no aliasing sync)
    if (tid < NK * NCH) {
      float v;
      if (it == 0) {
        v = cent[b * NK * NCH + tid];
      } else {
        const int k = tid / NCH, ch = tid - k * NCH;
        double* sb = &sums[((it - 1) % 3) * (NB * NK * 4) + b * NK * 4];
        double s = ald_f64(&sb[k * 4 + ch]);
        double n = ald_f64(&sb[k * 4 + 3]);
        v = (float)(s / n);                  // 0/0 -> NaN, matching reference
      }
      sm.p5.crbuf[tid] = v;
    }
    __syncthreads();
    // (2) broadcast to registers; knan per-thread (batch-uniform result)
    float cr[NK * NCH];
    {
      const float4* cp = (const float4*)sm.p5.crbuf;
      #pragma unroll
      for (int i = 0; i < 12; ++i) {
        float4 t4 = cp[i];
        cr[4 * i + 0] = t4.x; cr[4 * i + 1] = t4.y;
        cr[4 * i + 2] = t4.z; cr[4 * i + 3] = t4.w;
      }
    }
    int kn = -1;
    #pragma unroll
    for (int k = NK - 1; k >= 0; --k) {      // descending so lowest k wins
      float a = cr[3 * k], bb2 = cr[3 * k + 1], cc2 = cr[3 * k + 2];
      if (a != a || bb2 != bb2 || cc2 != cc2) kn = k;
    }
    // (3') self-zero OWN column (private -> NO sync needed before compute);
    // also zero next-parity global buffer (write-through atomic store).
    {
      float4 z4 = make_float4(0.f, 0.f, 0.f, 0.f);
      float4* zp = (float4*)&accf[tid * TSTRIDE];
      #pragma unroll
      for (int i = 0; i < 17; ++i) zp[i] = z4;
      if (tid < NK * 4)
        ast_f64(&sums[((it + 1) % 3) * (NB * NK * 4) + b * NK * 4 + tid], 0.0);
    }
    // (4) pixel loop: rolled 1-ahead register pipeline (R13) + b128
    // accumulate (R14) into the PRIVATE column. Same per-thread j order
    // and per-address f32 add order as R7/R13/R14 -> identical partials.
    {
      float* a0 = &accf[tid * TSTRIDE];
      float4 A = px4[3 * tid], B = px4[3 * tid + 1], C = px4[3 * tid + 2];
      float4 An = make_float4(0.f, 0.f, 0.f, 0.f);
      float4 Bn = An, Cn = An;
      #pragma unroll 1
      for (int j = tid; j < NQUADS; j += 256) {
        const int jn = j + 256;
        if (jn < NQUADS) {                 // prefetch next stage
          An = px4[3 * jn]; Bn = px4[3 * jn + 1]; Cn = px4[3 * jn + 2];
        }
        COMPQ(A, B, C);
        A = An; B = Bn; C = Cn;
      }
    }
    __syncthreads();
    // (5) reduce: thread (r=tid&63, q=tid>>6) sums the same logical
    // elements in the same rotated f64 order as R13/R14: column t's value
    // for row r lives at accf[t*68+r].
    double part = 0.0;
    {
      const int r = tid & 63, q = tid >> 6;
      const int s0 = r & 15;
      #pragma unroll
      for (int m = 0; m < 16; ++m) {
        const int c0 = q * 64 + (((m + s0) & 15) << 2);
        part += (double)accf[(c0 + 0) * TSTRIDE + r];
        part += (double)accf[(c0 + 1) * TSTRIDE + r];
        part += (double)accf[(c0 + 2) * TSTRIDE + r];
        part += (double)accf[(c0 + 3) * TSTRIDE + r];
      }
    }
    __syncthreads();
    {
      double* red = (double*)accf;       // reuse low 2KB as f64 scratch
      red[tid] = part;
      __syncthreads();
      if (tid < 64) {
        double tot = red[tid] + red[64 + tid] + red[128 + tid] + red[192 + tid];
        atomicAdd(&sums[(it % 3) * (NB * NK * 4) + b * NK * 4 + tid], tot);
      }
    }
    bbar_light(bar, b, ph);
  }

  // final centroids -> out (chunk-0 blocks write; coherent reads)
  if (c == 0 && tid < NK * NCH) {
    const int k = tid / NCH, ch = tid - k * NCH;
    double* sb = &sums[((NITER - 1) % 3) * (NB * NK * 4) + b * NK * 4];
    out[b * NK * NCH + tid] = (float)(ald_f64(&sb[k * 4 + ch]) /
                                      ald_f64(&sb[k * 4 + 3]));
  }
}

// ---------------------------------------------------------------------------
// Fallback path (ws too small): R1-verified monolithic kinit + R2 loop.
// ---------------------------------------------------------------------------
__global__ __launch_bounds__(256) void kinit_mono(const float* __restrict__ x,
                                                  float* __restrict__ cent,
                                                  float* __restrict__ sums) {
  const int b = (int)blockIdx.x;
  const int tid = (int)threadIdx.x;
  __shared__ u64 cand[CANDCAP];
  __shared__ u64 coll[NK][COLLCAP];
  __shared__ uint32_t hist[HBINS];
  __shared__ uint32_t Rtgt[NK];
  __shared__ uint32_t binsel[NK];
  __shared__ uint32_t rem[NK];
  __shared__ int jsel[NK];
  __shared__ int ncand;
  __shared__ int ncoll[NK];
  KeyPair S1, S2;
  derive_keys(b, S1, S2);
  if (tid == 0) ncand = 0;
  if (tid < NK) ncoll[tid] = 0;
  for (int i = tid; i < HBINS; i += 256) hist[i] = 0u;
  __syncthreads();
  for (int i = tid; i < NPIX; i += 256) {
    uint32_t k2 = sortkey(S2, (uint32_t)i);
    if (k2 < T2VAL) {
      int p = atomicAdd(&ncand, 1);
      if (p < CANDCAP) cand[p] = ((u64)k2 << 32) | (uint32_t)i;
    }
    uint32_t k1 = sortkey(S1, (uint32_t)i);
    atomicAdd(&hist[k1 >> 21], 1u);
  }
  __syncthreads();
  const int M = ncand < CANDCAP ? ncand : CANDCAP;
  for (int j = tid; j < M; j += 256) {
    u64 me = cand[j];
    int rank = 0;
    for (int t = 0; t < M; ++t) rank += (cand[t] < me) ? 1 : 0;
    if (rank < NK) Rtgt[rank] = (uint32_t)(me & 0xffffffffu);
  }
  __syncthreads();
  if (tid < NK) {
    uint32_t R = Rtgt[tid], cum = 0u, bin = 0u;
    for (int i = 0; i < HBINS; ++i) {
      uint32_t h = hist[i];
      if (R < cum + h) { bin = (uint32_t)i; break; }
      cum += h;
    }
    binsel[tid] = bin;
    rem[tid] = R - cum;
  }
  __syncthreads();
  for (int i = tid; i < NPIX; i += 256) {
    uint32_t k1 = sortkey(S1, (uint32_t)i);
    uint32_t pb = k1 >> 21;
    #pragma unroll
    for (int t = 0; t < NK; ++t) {
      if (pb == binsel[t]) {
        int p = atomicAdd(&ncoll[t], 1);
        if (p < COLLCAP) coll[t][p] = ((u64)k1 << 32) | (uint32_t)i;
      }
    }
  }
  __syncthreads();
  if (tid < NK) {
    int m = ncoll[tid] < COLLCAP ? ncoll[tid] : COLLCAP;
    uint32_t r = rem[tid];
    u64 lo = 0ULL, cur = ~0ULL;
    bool first = true;
    for (uint32_t pass = 0; pass <= r; ++pass) {
      cur = ~0ULL;
      for (int t = 0; t < m; ++t) {
        u64 v = coll[tid][t];
        if ((first || v > lo) && v < cur) cur = v;
      }
      lo = cur; first = false;
    }
    jsel[tid] = (int)(cur & 0xffffffffu);
  }
  __syncthreads();
  if (tid < NK * NCH) {
    int k = tid / NCH, c = tid % NCH;
    cent[(b * NK + k) * NCH + c] = x[((size_t)b * NPIX + (size_t)jsel[k]) * NCH + c];
  }
  if (tid < NK * 4) sums[b * NK * 4 + tid] = 0.0f;
}

__global__ __launch_bounds__(256) void kassign(const float* __restrict__ x,
                                               const float* __restrict__ cent,
                                               float* __restrict__ sums) {
  const int b = (int)blockIdx.y;
  const int tid = (int)threadIdx.x;
  __shared__ float cs[NK * NCH];
  __shared__ float acc[4][NK * 4];
  __shared__ int knan_s;
  if (tid < NK * NCH) cs[tid] = cent[b * NK * NCH + tid];
  acc[tid >> 6][tid & 63] = 0.0f;
  __syncthreads();
  if (tid == 0) {
    int kn = -1;
    for (int k = 0; k < NK; ++k) {
      float a = cs[3 * k], bb = cs[3 * k + 1], cc = cs[3 * k + 2];
      if (a != a || bb != bb || cc != cc) { kn = k; break; }
    }
    knan_s = kn;
  }
  __syncthreads();
  float cr[NK * NCH];
  #pragma unroll
  for (int i = 0; i < NK * NCH; ++i) cr[i] = cs[i];
  const float* xb = x + (size_t)b * NPIX * NCH;
  const float4* p = (const float4*)(xb + (size_t)blockIdx.x * 3072);
  const float4 A = p[3 * tid], Bv = p[3 * tid + 1], Cv = p[3 * tid + 2];
  const float px[4][3] = {{A.x, A.y, A.z}, {A.w, Bv.x, Bv.y},
                          {Bv.z, Bv.w, Cv.x}, {Cv.y, Cv.z, Cv.w}};
  float* a0 = acc[tid >> 6];
  const int kn = knan_s;
  #pragma unroll
  for (int q = 0; q < 4; ++q) {
    const float v0 = px[q][0], v1 = px[q][1], v2 = px[q][2];
    int best = 0;
    float bd = 3.402823466e38f;
    #pragma unroll
    for (int k = 0; k < NK; ++k) {
      float d0 = __fsub_rn(v0, cr[3 * k + 0]);
      float d1 = __fsub_rn(v1, cr[3 * k + 1]);
      float d2 = __fsub_rn(v2, cr[3 * k + 2]);
      float d = __fadd_rn(__fadd_rn(__fmul_rn(d0, d0), __fmul_rn(d1, d1)),
                          __fmul_rn(d2, d2));
      bool cnd = d < bd;
      bd = cnd ? d : bd;
      best = cnd ? k : best;
    }
    if (kn >= 0) best = kn;
    atomicAdd(&a0[best * 4 + 0], v0);
    atomicAdd(&a0[best * 4 + 1], v1);
    atomicAdd(&a0[best * 4 + 2], v2);
    atomicAdd(&a0[best * 4 + 3], 1.0f);
  }
  __syncthreads();
  if (tid < NK * 4) {
    float v = acc[0][tid] + acc[1][tid] + acc[2][tid] + acc[3][tid];
    atomicAdd(&sums[b * NK * 4 + tid], v);
  }
}

__global__ __launch_bounds__(64) void kupdate(float* __restrict__ cent,
                                              float* __restrict__ sums,
                                              float* __restrict__ out) {
  const int b = (int)blockIdx.x;
  const int t = (int)threadIdx.x;
  float v = 0.0f;
  if (t < NK * NCH) {
    const int k = t / NCH, c = t % NCH;
    v = sums[b * NK * 4 + k * 4 + c] / sums[b * NK * 4 + k * 4 + 3];
  }
  __syncthreads();
  if (t < NK * NCH) {
    cent[b * NK * NCH + t] = v;
    out[b * NK * NCH + t] = v;
  }
  sums[b * NK * 4 + t] = 0.0f;
}

extern "C" void kernel_launch(void* const* d_in, const int* in_sizes, int n_in,
                              void* d_out, int out_size, void* d_ws, size_t ws_size,
                              hipStream_t stream) {
  (void)in_sizes; (void)n_in; (void)out_size;
  const float* x = (const float*)d_in[0];
  float* out = (float*)d_out;
  char* ws = (char*)d_ws;

  // ws layout (bytes)
  float*    cent   = (float*)(ws + 0);              // 12288
  double*   sums   = (double*)(ws + 12288);         // 98304 (3 parity bufs)
  uint32_t* ncand  = (uint32_t*)(ws + 110592);      // 256    } zero
  uint32_t* ncoll  = (uint32_t*)(ws + 110848);      // 4096   } zone
  uint32_t* bar    = (uint32_t*)(ws + 114944);      // 1024   } 110592..
  uint32_t* hist   = (uint32_t*)(ws + 115968);      // 524288 } ..640256
  uint32_t* binsel = (uint32_t*)(ws + 640256);      // 4096
  uint32_t* rem    = (uint32_t*)(ws + 644352);      // 4096
  u64*      cand   = (u64*)(ws + 648448);           // 524288
  u64*      coll   = (u64*)(ws + 1172736);          // 1048576
  const size_t REQ = 2221312;

  if (ws_size >= REQ) {
    hipMemsetAsync(ws + 110592, 0, 529664, stream);
    mega<<<NBLK, 256, 0, stream>>>(x, out, cent, sums, ncand, ncoll, bar,
                                   hist, binsel, rem, cand, coll);
  } else {
    float* centf = (float*)ws;                 // fallback: f32 sums layout
    float* sumsf = centf + NB * NK * NCH;
    kinit_mono<<<NB, 256, 0, stream>>>(x, centf, sumsf);
    for (int it = 0; it < NITER; ++it) {
      kassign<<<dim3(49, NB), 256, 0, stream>>>(x, centf, sumsf);
      kupdate<<<NB, 64, 0, stream>>>(centf, sumsf, out);
    }
  }
}

// Round 23
// 470.551 us; speedup vs baseline: 1.0233x; 1.0222x over previous
//
#include <hip/hip_runtime.h>
#include <stdint.h>

// ---------------------------------------------------------------------------
// ColorExtractor: per-image k-means (B=64, H*W=50176, C=3, K=16, 10 iters).
// Threefry2x32 bit-exact (verified R1, absmax 0.0).
// R16 (6th resubmit; R17-R22 benches lost to GPUAcquisitionTimeout): deepen
// the global prefetch to 2-AHEAD. Evidence chain: R13's 1-ahead global
// prefetch = only verified win since R7 (455->434); R14 (b128 LDS
// accumulate) and R15 (sync cuts) both neutral; R14/R15 run 20x higher LDS
// bank conflicts than R13 at IDENTICAL timing -> LDS not critical path.
// VALUBusy*dur ~150us invariant 4 rounds; VALUBusy 35% at 2 waves/SIMD ->
// residual ~280us is GLOBAL latency (working set 4.8MB/XCD > 4MB L2 ->
// L3 misses ~600-900cy; 1-ahead cover has gaps). R16 loads stage j+512
// while computing j: 3 buffer sets (36 VGPR total), ~3600cy cover.
// Register budget: 88 + 12 ~= 100-112 <= 128 cap -> no spill.
// Numerics: loads are pure reads; per-thread COMPQ order unchanged ->
// identical f32 partials -> absmax 0.0.
// Config (locked by R7-R15 map): launch_bounds(256,2) = 128-VGPR cap +
// 2 blk/CU. R15 kept: crbuf staging + self-zero (4 syncs/iter).
// Numerics-critical invariants (DO NOT CHANGE): pixel->thread partition
// (8 chunks x 256 threads, j stride 256 ascending), per-thread per-address
// f32 add order, f64 column reduce order, _rn chain, first-NaN argmin.
// R7 kept: per-batch 8-block barriers (monotonic counter), release-only
// light barriers + agent atomics in the loop, full acq/rel in init.
// ---------------------------------------------------------------------------

#define NB    64
#define NPIX  50176
#define NK    16
#define NCH   3
#define NITER 10
#define HBINS 2048
#define CANDCAP 1024     // expect ~320 cands/batch (T2VAL), huge margin
#define COLLCAP 128      // expect ~24.5/bin
#define NBLK  512        // 8 chunks x 64 batches; 2 blocks/CU on 256 CUs
#define CHUNK (NPIX / 8) // 6272 px per block-chunk
#define NQUADS (CHUNK / 4)  // 1568 = 6*256 + 32
#define TSTRIDE 68       // per-thread accf stride: 16*4 + 4 pad (bank spread)

typedef unsigned long long u64;

struct KeyPair { uint32_t a, b; };

__device__ __forceinline__ uint32_t rotl32(uint32_t v, uint32_t r) {
  return (v << r) | (v >> (32u - r));
}
__device__ __forceinline__ void tf_round(uint32_t& x0, uint32_t& x1, uint32_t r) {
  x0 += x1; x1 = rotl32(x1, r); x1 ^= x0;
}

// Threefry-2x32, 20 rounds, exactly as jax/_src/prng.py lowering.
__device__ __forceinline__ KeyPair threefry(uint32_t k0, uint32_t k1,
                                            uint32_t x0, uint32_t x1) {
  const uint32_t ks2 = k0 ^ k1 ^ 0x1BD11BDAu;
  x0 += k0; x1 += k1;
  tf_round(x0, x1, 13u); tf_round(x0, x1, 15u); tf_round(x0, x1, 26u); tf_round(x0, x1, 6u);
  x0 += k1;  x1 += ks2 + 1u;
  tf_round(x0, x1, 17u); tf_round(x0, x1, 29u); tf_round(x0, x1, 16u); tf_round(x0, x1, 24u);
  x0 += ks2; x1 += k0 + 2u;
  tf_round(x0, x1, 13u); tf_round(x0, x1, 15u); tf_round(x0, x1, 26u); tf_round(x0, x1, 6u);
  x0 += k0;  x1 += k1 + 3u;
  tf_round(x0, x1, 17u); tf_round(x0, x1, 29u); tf_round(x0, x1, 16u); tf_round(x0, x1, 24u);
  x0 += k1;  x1 += ks2 + 4u;
  tf_round(x0, x1, 13u); tf_round(x0, x1, 15u); tf_round(x0, x1, 26u); tf_round(x0, x1, 6u);
  x0 += ks2; x1 += k0 + 5u;
  KeyPair r; r.a = x0; r.b = x1; return r;
}

__device__ __forceinline__ uint32_t sortkey(KeyPair S, uint32_t i) {
  KeyPair r = threefry(S.a, S.b, 0u, i);   // counter = 64-bit iota (hi=0,lo=i)
  return r.a ^ r.b;                        // 32-bit path XOR-folds the block
}

__device__ __forceinline__ void derive_keys(int b, KeyPair& S1, KeyPair& S2) {
  KeyPair root; root.a = 0u; root.b = 42u;
  KeyPair kb = threefry(root.a, root.b, 0u, (uint32_t)b);   // foldlike split
  KeyPair K1 = threefry(kb.a, kb.b, 0u, 0u);
  S1 = threefry(kb.a, kb.b, 0u, 1u);                        // round-1 subkey
  S2 = threefry(K1.a, K1.b, 0u, 1u);                        // round-2 subkey
}

#define T2VAL 27394240u  // ~2^32*320/NPIX

// ---- agent-scope per-address coherent accessors (bypass stale L1/L2) ------
__device__ __forceinline__ uint32_t ald_u32(const uint32_t* p) {
  return __hip_atomic_load(p, __ATOMIC_RELAXED, __HIP_MEMORY_SCOPE_AGENT);
}
__device__ __forceinline__ void ast_f64(double* p, double v) {
  __hip_atomic_store(p, v, __ATOMIC_RELAXED, __HIP_MEMORY_SCOPE_AGENT);
}
__device__ __forceinline__ double ald_f64(const double* p) {
  return __hip_atomic_load(p, __ATOMIC_RELAXED, __HIP_MEMORY_SCOPE_AGENT);
}

// ---- per-batch barriers (8 participants = the 8 chunk-blocks of batch b) --
// Slot: bar + b*4 u32. Monotonic arrival counter (zeroed at launch); each
// block keeps local phase ph; barrier #ph completes when count >= 8*ph.

// Full barrier (init phases): release fence (wbl2) before arrival, acquire
// fence (buffer_inv) on exit -> plain loads/stores safe across it.
__device__ __forceinline__ void bbar_full(uint32_t* bar, int b, int& ph) {
  __syncthreads();
  if (threadIdx.x == 0) {
    uint32_t* slot = bar + (b << 2);
    ph += 1;
    const uint32_t tgt = (uint32_t)(ph << 3);
    __builtin_amdgcn_fence(__ATOMIC_RELEASE, "agent");  // wbl2: publish writes
    __hip_atomic_fetch_add(slot, 1u, __ATOMIC_RELEASE, __HIP_MEMORY_SCOPE_AGENT);
    while (__hip_atomic_load(slot, __ATOMIC_RELAXED,
                             __HIP_MEMORY_SCOPE_AGENT) < tgt)
      __builtin_amdgcn_s_sleep(4);
    __builtin_amdgcn_fence(__ATOMIC_ACQUIRE, "agent");  // buffer_inv (once)
  }
  __syncthreads();
}

// Light barrier (k-means loop): release-only arrival, relaxed spin, NO
// acquire (keeps caches warm). Cross-block data after this barrier MUST
// use agent atomic ld/st (ald/ast/atomicAdd).
__device__ __forceinline__ void bbar_light(uint32_t* bar, int b, int& ph) {
  __syncthreads();
  if (threadIdx.x == 0) {
    uint32_t* slot = bar + (b << 2);
    ph += 1;
    const uint32_t tgt = (uint32_t)(ph << 3);
    __hip_atomic_fetch_add(slot, 1u, __ATOMIC_RELEASE, __HIP_MEMORY_SCOPE_AGENT);
    while (__hip_atomic_load(slot, __ATOMIC_RELAXED,
                             __HIP_MEMORY_SCOPE_AGENT) < tgt)
      __builtin_amdgcn_s_sleep(4);
    // no acquire fence
  }
  __syncthreads();
}

union SMem {
  struct { uint32_t lh[HBINS]; } p1;
  struct { u64 sc[CANDCAP]; uint32_t sh[HBINS]; uint32_t S[HBINS];
           uint32_t ts[256]; uint32_t Rt[NK]; } p2;
  struct { uint32_t bs[NK]; } p3;
  struct { u64 lc[NK * COLLCAP]; int jsel[NK]; } p4;
  // ~70 KB: thread t owns accf[t*68 .. t*68+63] (16 clusters x
  // {c0,c1,c2,cnt} + 4 pad). crbuf separate (R15) -> fewer syncs.
  struct { float accf[256 * TSTRIDE]; float crbuf[48]; } p5;
};

// compute one stage from named regs; vectorized b128 accumulate (R14).
// Per-address f32 add order identical to the scalar-RMW form.
#define COMPQ(A_, B_, C_) do {                                                \
      const float qx[4][3] = {{A_.x, A_.y, A_.z}, {A_.w, B_.x, B_.y},         \
                              {B_.z, B_.w, C_.x}, {C_.y, C_.z, C_.w}};        \
      _Pragma("unroll")                                                       \
      for (int q = 0; q < 4; ++q) {                                           \
        const float v0 = qx[q][0], v1 = qx[q][1], v2 = qx[q][2];              \
        int best = 0;                                                         \
        float bd = 3.402823466e38f;                                           \
        _Pragma("unroll")                                                     \
        for (int k = 0; k < NK; ++k) {  /* _rn chain, strict <, asc. k */     \
          float d0 = __fsub_rn(v0, cr[3 * k + 0]);                            \
          float d1 = __fsub_rn(v1, cr[3 * k + 1]);                            \
          float d2 = __fsub_rn(v2, cr[3 * k + 2]);                            \
          float d = __fadd_rn(__fadd_rn(__fmul_rn(d0, d0), __fmul_rn(d1, d1)),\
                              __fmul_rn(d2, d2));                             \
          bool cnd = d < bd;                                                  \
          bd = cnd ? d : bd;                                                  \
          best = cnd ? k : best;                                              \
        }                                                                     \
        if (kn >= 0) best = kn;        /* np.argmin: first NaN wins */        \
        float4* pacc = (float4*)&a0[best << 2];                               \
        float4 o = *pacc;                                                     \
        o.x += v0; o.y += v1; o.z += v2; o.w += 1.0f;                         \
        *pacc = o;                                                            \
      }                                                                       \
    } while (0)

__global__ __launch_bounds__(256, 2) void mega(
    const float* __restrict__ x, float* __restrict__ out,
    float* __restrict__ cent, double* __restrict__ sums,
    uint32_t* __restrict__ ncand, uint32_t* __restrict__ ncoll,
    uint32_t* __restrict__ bar, uint32_t* __restrict__ hist,
    uint32_t* __restrict__ binsel, uint32_t* __restrict__ rem,
    u64* __restrict__ cand, u64* __restrict__ coll) {
  __shared__ SMem sm;
  const int blk = (int)blockIdx.x;
  const int tid = (int)threadIdx.x;
  const int b = blk >> 3;        // batch
  const int c = blk & 7;         // chunk within batch
  int ph = 0;                    // per-batch barrier phase (used by tid 0)

  KeyPair S1, S2;
  derive_keys(b, S1, S2);

  // ---- P1: key2 candidate filter + key1 prefix histogram ----
  for (int i = tid; i < HBINS; i += 256) sm.p1.lh[i] = 0u;
  __syncthreads();
  {
    const int start = c * CHUNK;
    for (int i = start + tid; i < start + CHUNK; i += 256) {
      uint32_t k2 = sortkey(S2, (uint32_t)i);
      if (k2 < T2VAL) {
        uint32_t p = atomicAdd(&ncand[b], 1u);
        if (p < CANDCAP) cand[b * CANDCAP + p] = ((u64)k2 << 32) | (uint32_t)i;
      }
      uint32_t k1 = sortkey(S1, (uint32_t)i);
      atomicAdd(&sm.p1.lh[k1 >> 21], 1u);
    }
    __syncthreads();
    for (int i = tid; i < HBINS; i += 256)
      if (sm.p1.lh[i]) atomicAdd(&hist[b * HBINS + i], sm.p1.lh[i]);
  }
  bbar_full(bar, b, ph);

  // ---- P2 (chunk-0 block of each batch): rank candidates, scan hist,
  //      binary search ----
  if (c == 0) {
    const int bb = b;
    uint32_t nc = ald_u32(&ncand[bb]);   // uniform addr: keep atomic load
    const int M = nc < CANDCAP ? (int)nc : CANDCAP;
    for (int i = tid; i < M; i += 256) sm.p2.sc[i] = cand[bb * CANDCAP + i];
    for (int i = tid; i < HBINS; i += 256) sm.p2.sh[i] = hist[bb * HBINS + i];
    __syncthreads();
    // top-16 rank under (key2, idx); distinct pairs -> unique ranks
    for (int j = tid; j < M; j += 256) {
      u64 me = sm.p2.sc[j];
      int r = 0;
      for (int t = 0; t < M; ++t) r += (sm.p2.sc[t] < me) ? 1 : 0;
      if (r < NK) sm.p2.Rt[r] = (uint32_t)(me & 0xffffffffu);
    }
    // parallel inclusive scan of sh -> S (8 bins/thread + block scan)
    uint32_t loc[8]; uint32_t run = 0;
    for (int j = 0; j < 8; ++j) { run += sm.p2.sh[tid * 8 + j]; loc[j] = run; }
    sm.p2.ts[tid] = run;
    __syncthreads();
    for (int off = 1; off < 256; off <<= 1) {
      uint32_t v = (tid >= off) ? sm.p2.ts[tid - off] : 0u;
      __syncthreads();
      sm.p2.ts[tid] += v;
      __syncthreads();
    }
    uint32_t excl = sm.p2.ts[tid] - run;
    for (int j = 0; j < 8; ++j) sm.p2.S[tid * 8 + j] = excl + loc[j];
    __syncthreads();
    if (tid < NK) {
      uint32_t R = sm.p2.Rt[tid];
      int lo = 0, hi = HBINS - 1;
      while (lo < hi) {                      // smallest i with S[i] > R
        int mid = (lo + hi) >> 1;
        if (sm.p2.S[mid] > R) hi = mid; else lo = mid + 1;
      }
      binsel[bb * NK + tid] = (uint32_t)lo;
      rem[bb * NK + tid] = R - (lo ? sm.p2.S[lo - 1] : 0u);
    }
  }
  bbar_full(bar, b, ph);

  // ---- P3: collect key1 elements landing in each target's bin ----
  {
    __shared__ uint32_t bs_s[NK];
    if (tid < NK) bs_s[tid] = binsel[b * NK + tid];
    __syncthreads();
    const int start = c * CHUNK;
    for (int i = start + tid; i < start + CHUNK; i += 256) {
      uint32_t k1 = sortkey(S1, (uint32_t)i);
      uint32_t pb = k1 >> 21;
      #pragma unroll
      for (int t = 0; t < NK; ++t) {
        if (pb == bs_s[t]) {
          uint32_t p = atomicAdd(&ncoll[b * NK + t], 1u);
          if (p < COLLCAP)
            coll[(b * NK + t) * COLLCAP + p] = ((u64)k1 << 32) | (uint32_t)i;
        }
      }
    }
  }
  bbar_full(bar, b, ph);

  // ---- P4 (chunk-0 block of each batch): stable rank-select, gather cent --
  if (c == 0) {
    const int bb = b;
    for (int i = tid; i < NK * COLLCAP; i += 256)
      sm.p4.lc[i] = coll[bb * NK * COLLCAP + i];
    __syncthreads();
    if (tid < NK) {
      uint32_t ncl = ncoll[bb * NK + tid];
      const int m = ncl < COLLCAP ? (int)ncl : COLLCAP;
      const uint32_t r = rem[bb * NK + tid];
      const u64* cc = &sm.p4.lc[tid * COLLCAP];
      u64 lo = 0ULL, cur = ~0ULL;
      bool first = true;
      for (uint32_t pass = 0; pass <= r; ++pass) {
        cur = ~0ULL;
        for (int i = 0; i < m; ++i) {
          u64 v = cc[i];
          if ((first || v > lo) && v < cur) cur = v;
        }
        lo = cur; first = false;
      }
      sm.p4.jsel[tid] = (int)(cur & 0xffffffffu);
    }
    __syncthreads();
    if (tid < NK * NCH) {
      int k = tid / NCH, ch = tid % NCH;
      cent[bb * NK * NCH + tid] =
          x[((size_t)bb * NPIX + (size_t)sm.p4.jsel[k]) * NCH + ch];
    }
  }
  bbar_full(bar, b, ph);

  // ---- P5: 10 k-means iterations, 1 LIGHT per-batch barrier each ----
  // All cross-block traffic via agent atomic ld/st + HW atomicAdd.
  const float4* px4 = (const float4*)(x + (size_t)b * NPIX * NCH + (size_t)c * (CHUNK * NCH));
  float* accf = sm.p5.accf;

  for (int it = 0; it < NITER; ++it) {
    // (1) new centroids -> crbuf (separate from accf -> no aliasing sync)
    if (tid < NK * NCH) {
      float v;
      if (it == 0) {
        v = cent[b * NK * NCH + tid];
      } else {
        const int k = tid / NCH, ch = tid - k * NCH;
        double* sb = &sums[((it - 1) % 3) * (NB * NK * 4) + b * NK * 4];
        double s = ald_f64(&sb[k * 4 + ch]);
        double n = ald_f64(&sb[k * 4 + 3]);
        v = (float)(s / n);                  // 0/0 -> NaN, matching reference
      }
      sm.p5.crbuf[tid] = v;
    }
    __syncthreads();
    // (2) broadcast to registers; knan per-thread (batch-uniform result)
    float cr[NK * NCH];
    {
      const float4* cp = (const float4*)sm.p5.crbuf;
      #pragma unroll
      for (int i = 0; i < 12; ++i) {
        float4 t4 = cp[i];
        cr[4 * i + 0] = t4.x; cr[4 * i + 1] = t4.y;
        cr[4 * i + 2] = t4.z; cr[4 * i + 3] = t4.w;
      }
    }
    int kn = -1;
    #pragma unroll
    for (int k = NK - 1; k >= 0; --k) {      // descending so lowest k wins
      float a = cr[3 * k], bb2 = cr[3 * k + 1], cc2 = cr[3 * k + 2];
      if (a != a || bb2 != bb2 || cc2 != cc2) kn = k;
    }
    // (3') self-zero OWN column (private -> NO sync needed before compute);
    // also zero next-parity global buffer (write-through atomic store).
    {
      float4 z4 = make_float4(0.f, 0.f, 0.f, 0.f);
      float4* zp = (float4*)&accf[tid * TSTRIDE];
      #pragma unroll
      for (int i = 0; i < 17; ++i) zp[i] = z4;
      if (tid < NK * 4)
        ast_f64(&sums[((it + 1) % 3) * (NB * NK * 4) + b * NK * 4 + tid], 0.0);
    }
    // (4) pixel loop: rolled 2-AHEAD register pipeline (R16) + b128
    // accumulate (R14) into the PRIVATE column. Loads for stage j+512
    // issue during compute of stage j (~3600cy cover vs L3 ~900cy).
    // Same per-thread j order and per-address f32 add order as R7/R13 ->
    // identical partials.
    {
      float* a0 = &accf[tid * TSTRIDE];
      const float4 z4 = make_float4(0.f, 0.f, 0.f, 0.f);
      float4 A = px4[3 * tid], B = px4[3 * tid + 1], C = px4[3 * tid + 2];
      float4 An = z4, Bn = z4, Cn = z4;
      {
        const int j1 = tid + 256;
        if (j1 < NQUADS) {
          An = px4[3 * j1]; Bn = px4[3 * j1 + 1]; Cn = px4[3 * j1 + 2];
        }
      }
      #pragma unroll 1
      for (int j = tid; j < NQUADS; j += 256) {
        const int j2 = j + 512;
        float4 A2 = z4, B2 = z4, C2 = z4;
        if (j2 < NQUADS) {                 // prefetch stage j+512
          A2 = px4[3 * j2]; B2 = px4[3 * j2 + 1]; C2 = px4[3 * j2 + 2];
        }
        COMPQ(A, B, C);
        A = An; B = Bn; C = Cn;
        An = A2; Bn = B2; Cn = C2;
      }
    }
    __syncthreads();
    // (5) reduce: thread (r=tid&63, q=tid>>6) sums the same logical
    // elements in the same rotated f64 order as R13/R14: column t's value
    // for row r lives at accf[t*68+r].
    double part = 0.0;
    {
      const int r = tid & 63, q = tid >> 6;
      const int s0 = r & 15;
      #pragma unroll
      for (int m = 0; m < 16; ++m) {
        const int c0 = q * 64 + (((m + s0) & 15) << 2);
        part += (double)accf[(c0 + 0) * TSTRIDE + r];
        part += (double)accf[(c0 + 1) * TSTRIDE + r];
        part += (double)accf[(c0 + 2) * TSTRIDE + r];
        part += (double)accf[(c0 + 3) * TSTRIDE + r];
      }
    }
    __syncthreads();
    {
      double* red = (double*)accf;       // reuse low 2KB as f64 scratch
      red[tid] = part;
      __syncthreads();
      if (tid < 64) {
        double tot = red[tid] + red[64 + tid] + red[128 + tid] + red[192 + tid];
        atomicAdd(&sums[(it % 3) * (NB * NK * 4) + b * NK * 4 + tid], tot);
      }
    }
    bbar_light(bar, b, ph);
  }

  // final centroids -> out (chunk-0 blocks write; coherent reads)
  if (c == 0 && tid < NK * NCH) {
    const int k = tid / NCH, ch = tid - k * NCH;
    double* sb = &sums[((NITER - 1) % 3) * (NB * NK * 4) + b * NK * 4];
    out[b * NK * NCH + tid] = (float)(ald_f64(&sb[k * 4 + ch]) /
                                      ald_f64(&sb[k * 4 + 3]));
  }
}

// ---------------------------------------------------------------------------
// Fallback path (ws too small): R1-verified monolithic kinit + R2 loop.
// ---------------------------------------------------------------------------
__global__ __launch_bounds__(256) void kinit_mono(const float* __restrict__ x,
                                                  float* __restrict__ cent,
                                                  float* __restrict__ sums) {
  const int b = (int)blockIdx.x;
  const int tid = (int)threadIdx.x;
  __shared__ u64 cand[CANDCAP];
  __shared__ u64 coll[NK][COLLCAP];
  __shared__ uint32_t hist[HBINS];
  __shared__ uint32_t Rtgt[NK];
  __shared__ uint32_t binsel[NK];
  __shared__ uint32_t rem[NK];
  __shared__ int jsel[NK];
  __shared__ int ncand;
  __shared__ int ncoll[NK];
  KeyPair S1, S2;
  derive_keys(b, S1, S2);
  if (tid == 0) ncand = 0;
  if (tid < NK) ncoll[tid] = 0;
  for (int i = tid; i < HBINS; i += 256) hist[i] = 0u;
  __syncthreads();
  for (int i = tid; i < NPIX; i += 256) {
    uint32_t k2 = sortkey(S2, (uint32_t)i);
    if (k2 < T2VAL) {
      int p = atomicAdd(&ncand, 1);
      if (p < CANDCAP) cand[p] = ((u64)k2 << 32) | (uint32_t)i;
    }
    uint32_t k1 = sortkey(S1, (uint32_t)i);
    atomicAdd(&hist[k1 >> 21], 1u);
  }
  __syncthreads();
  const int M = ncand < CANDCAP ? ncand : CANDCAP;
  for (int j = tid; j < M; j += 256) {
    u64 me = cand[j];
    int rank = 0;
    for (int t = 0; t < M; ++t) rank += (cand[t] < me) ? 1 : 0;
    if (rank < NK) Rtgt[rank] = (uint32_t)(me & 0xffffffffu);
  }
  __syncthreads();
  if (tid < NK) {
    uint32_t R = Rtgt[tid], cum = 0u, bin = 0u;
    for (int i = 0; i < HBINS; ++i) {
      uint32_t h = hist[i];
      if (R < cum + h) { bin = (uint32_t)i; break; }
      cum += h;
    }
    binsel[tid] = bin;
    rem[tid] = R - cum;
  }
  __syncthreads();
  for (int i = tid; i < NPIX; i += 256) {
    uint32_t k1 = sortkey(S1, (uint32_t)i);
    uint32_t pb = k1 >> 21;
    #pragma unroll
    for (int t = 0; t < NK; ++t) {
      if (pb == binsel[t]) {
        int p = atomicAdd(&ncoll[t], 1);
        if (p < COLLCAP) coll[t][p] = ((u64)k1 << 32) | (uint32_t)i;
      }
    }
  }
  __syncthreads();
  if (tid < NK) {
    int m = ncoll[tid] < COLLCAP ? ncoll[tid] : COLLCAP;
    uint32_t r = rem[tid];
    u64 lo = 0ULL, cur = ~0ULL;
    bool first = true;
    for (uint32_t pass = 0; pass <= r; ++pass) {
      cur = ~0ULL;
      for (int t = 0; t < m; ++t) {
        u64 v = coll[tid][t];
        if ((first || v > lo) && v < cur) cur = v;
      }
      lo = cur; first = false;
    }
    jsel[tid] = (int)(cur & 0xffffffffu);
  }
  __syncthreads();
  if (tid < NK * NCH) {
    int k = tid / NCH, c = tid % NCH;
    cent[(b * NK + k) * NCH + c] = x[((size_t)b * NPIX + (size_t)jsel[k]) * NCH + c];
  }
  if (tid < NK * 4) sums[b * NK * 4 + tid] = 0.0f;
}

__global__ __launch_bounds__(256) void kassign(const float* __restrict__ x,
                                               const float* __restrict__ cent,
                                               float* __restrict__ sums) {
  const int b = (int)blockIdx.y;
  const int tid = (int)threadIdx.x;
  __shared__ float cs[NK * NCH];
  __shared__ float acc[4][NK * 4];
  __shared__ int knan_s;
  if (tid < NK * NCH) cs[tid] = cent[b * NK * NCH + tid];
  acc[tid >> 6][tid & 63] = 0.0f;
  __syncthreads();
  if (tid == 0) {
    int kn = -1;
    for (int k = 0; k < NK; ++k) {
      float a = cs[3 * k], bb = cs[3 * k + 1], cc = cs[3 * k + 2];
      if (a != a || bb != bb || cc != cc) { kn = k; break; }
    }
    knan_s = kn;
  }
  __syncthreads();
  float cr[NK * NCH];
  #pragma unroll
  for (int i = 0; i < NK * NCH; ++i) cr[i] = cs[i];
  const float* xb = x + (size_t)b * NPIX * NCH;
  const float4* p = (const float4*)(xb + (size_t)blockIdx.x * 3072);
  const float4 A = p[3 * tid], Bv = p[3 * tid + 1], Cv = p[3 * tid + 2];
  const float px[4][3] = {{A.x, A.y, A.z}, {A.w, Bv.x, Bv.y},
                          {Bv.z, Bv.w, Cv.x}, {Cv.y, Cv.z, Cv.w}};
  float* a0 = acc[tid >> 6];
  const int kn = knan_s;
  #pragma unroll
  for (int q = 0; q < 4; ++q) {
    const float v0 = px[q][0], v1 = px[q][1], v2 = px[q][2];
    int best = 0;
    float bd = 3.402823466e38f;
    #pragma unroll
    for (int k = 0; k < NK; ++k) {
      float d0 = __fsub_rn(v0, cr[3 * k + 0]);
      float d1 = __fsub_rn(v1, cr[3 * k + 1]);
      float d2 = __fsub_rn(v2, cr[3 * k + 2]);
      float d = __fadd_rn(__fadd_rn(__fmul_rn(d0, d0), __fmul_rn(d1, d1)),
                          __fmul_rn(d2, d2));
      bool cnd = d < bd;
      bd = cnd ? d : bd;
      best = cnd ? k : best;
    }
    if (kn >= 0) best = kn;
    atomicAdd(&a0[best * 4 + 0], v0);
    atomicAdd(&a0[best * 4 + 1], v1);
    atomicAdd(&a0[best * 4 + 2], v2);
    atomicAdd(&a0[best * 4 + 3], 1.0f);
  }
  __syncthreads();
  if (tid < NK * 4) {
    float v = acc[0][tid] + acc[1][tid] + acc[2][tid] + acc[3][tid];
    atomicAdd(&sums[b * NK * 4 + tid], v);
  }
}

__global__ __launch_bounds__(64) void kupdate(float* __restrict__ cent,
                                              float* __restrict__ sums,
                                              float* __restrict__ out) {
  const int b = (int)blockIdx.x;
  const int t = (int)threadIdx.x;
  float v = 0.0f;
  if (t < NK * NCH) {
    const int k = t / NCH, c = t % NCH;
    v = sums[b * NK * 4 + k * 4 + c] / sums[b * NK * 4 + k * 4 + 3];
  }
  __syncthreads();
  if (t < NK * NCH) {
    cent[b * NK * NCH + t] = v;
    out[b * NK * NCH + t] = v;
  }
  sums[b * NK * 4 + t] = 0.0f;
}

extern "C" void kernel_launch(void* const* d_in, const int* in_sizes, int n_in,
                              void* d_out, int out_size, void* d_ws, size_t ws_size,
                              hipStream_t stream) {
  (void)in_sizes; (void)n_in; (void)out_size;
  const float* x = (const float*)d_in[0];
  float* out = (float*)d_out;
  char* ws = (char*)d_ws;

  // ws layout (bytes)
  float*    cent   = (float*)(ws + 0);              // 12288
  double*   sums   = (double*)(ws + 12288);         // 98304 (3 parity bufs)
  uint32_t* ncand  = (uint32_t*)(ws + 110592);      // 256    } zero
  uint32_t* ncoll  = (uint32_t*)(ws + 110848);      // 4096   } zone
  uint32_t* bar    = (uint32_t*)(ws + 114944);      // 1024   } 110592..
  uint32_t* hist   = (uint32_t*)(ws + 115968);      // 524288 } ..640256
  uint32_t* binsel = (uint32_t*)(ws + 640256);      // 4096
  uint32_t* rem    = (uint32_t*)(ws + 644352);      // 4096
  u64*      cand   = (u64*)(ws + 648448);           // 524288
  u64*      coll   = (u64*)(ws + 1172736);          // 1048576
  const size_t REQ = 2221312;

  if (ws_size >= REQ) {
    hipMemsetAsync(ws + 110592, 0, 529664, stream);
    mega<<<NBLK, 256, 0, stream>>>(x, out, cent, sums, ncand, ncoll, bar,
                                   hist, binsel, rem, cand, coll);
  } else {
    float* centf = (float*)ws;                 // fallback: f32 sums layout
    float* sumsf = centf + NB * NK * NCH;
    kinit_mono<<<NB, 256, 0, stream>>>(x, centf, sumsf);
    for (int it = 0; it < NITER; ++it) {
      kassign<<<dim3(49, NB), 256, 0, stream>>>(x, centf, sumsf);
      kupdate<<<NB, 64, 0, stream>>>(centf, sumsf, out);
    }
  }
}